// Round 12
// baseline (487.702 us; speedup 1.0000x reference)
//
#include <hip/hip_runtime.h>

#define N_NODES 50000
#define N_EDGES 1600000
#define F_IN 1433
#define HID 128
#define NCLS 7
#define KSTEPS 45

// ---- workspace layout (bytes), all 256-aligned ----
#define O_DEG_SRC 0u          // N ints   (200000)
#define O_DEG_DST 200704u     // N ints
#define O_CURSOR  401408u     // N ints
#define O_ROWPTR  602112u     // N+1 ints
#define O_NSRC    802816u     // N floats
#define O_NDST    1003520u    // N floats
#define O_BSUM    1204224u    // 256 ints
#define O_BOFF    1205248u    // 256 ints
#define O_CSR     1206272u    // E ints (6400000)
#define O_H       7606272u    // N*128 _Float16 (12800000), 16B aligned
#define O_H2      33206272u   // N*8 floats padded (1600000)
#define O_W1S     34806272u   // 45*2*4*128*8 shorts = 737280 B
#define O_HP0     35543552u   // k-split partials: NSPLIT x N*128 f32 (25600000 each)
#define HP_ELEMS  6400000

typedef __attribute__((ext_vector_type(8))) short s8v;      // 8 bf16 (4 VGPRs)
typedef __attribute__((ext_vector_type(4))) float f4v;      // 4 f32
typedef __attribute__((ext_vector_type(2))) _Float16 h2v;   // 2 fp16
typedef __attribute__((ext_vector_type(4))) _Float16 h4v;   // 4 fp16

// RNE f32 -> bf16 hi, residual -> bf16 lo (RNE, used for W1 prep)
__device__ __forceinline__ void split_bf16(float v, short& hi, short& lo) {
    unsigned u = __builtin_bit_cast(unsigned, v);
    unsigned r = u + 0x7FFFu + ((u >> 16) & 1u);
    unsigned short h = (unsigned short)(r >> 16);
    float hf = __builtin_bit_cast(float, (unsigned)h << 16);
    float lv = v - hf;
    unsigned u2 = __builtin_bit_cast(unsigned, lv);
    unsigned r2 = u2 + 0x7FFFu + ((u2 >> 16) & 1u);
    hi = (short)h;
    lo = (short)(r2 >> 16);
}

// cheaper variant for the per-step A split: lo truncated
__device__ __forceinline__ void split_bf16_t(float v, short& hi, short& lo) {
    unsigned u = __builtin_bit_cast(unsigned, v);
    unsigned r = u + 0x7FFFu + ((u >> 16) & 1u);
    unsigned short h = (unsigned short)(r >> 16);
    float hf = __builtin_bit_cast(float, (unsigned)h << 16);
    float lv = v - hf;
    hi = (short)h;
    lo = (short)(__builtin_bit_cast(unsigned, lv) >> 16);
}

__global__ void zero_ws_kernel(int4* __restrict__ p) {
    int i = blockIdx.x * 256 + threadIdx.x;
    if (i < 37632) p[i] = make_int4(0, 0, 0, 0);
}

__global__ void deg_kernel(const int* __restrict__ dst, int* __restrict__ deg_dst) {
    int e = blockIdx.x * blockDim.x + threadIdx.x;
    if (e < N_EDGES) atomicAdd(&deg_dst[dst[e]], 1);
}

__global__ void scan1_kernel(const int* __restrict__ deg, int* __restrict__ incl,
                             int* __restrict__ bsum) {
    __shared__ int s[256];
    int t = threadIdx.x;
    int i = blockIdx.x * 256 + t;
    int v = (i < N_NODES) ? deg[i] : 0;
    s[t] = v;
    __syncthreads();
    for (int off = 1; off < 256; off <<= 1) {
        int a = (t >= off) ? s[t - off] : 0;
        __syncthreads();
        s[t] += a;
        __syncthreads();
    }
    if (i < N_NODES) incl[i] = s[t];
    if (t == 255) bsum[blockIdx.x] = s[255];
}

__global__ void scan2_kernel(const int* __restrict__ bsum, int* __restrict__ boff, int nb) {
    __shared__ int s[256];
    int t = threadIdx.x;
    int v = (t < nb) ? bsum[t] : 0;
    s[t] = v;
    __syncthreads();
    for (int off = 1; off < 256; off <<= 1) {
        int a = (t >= off) ? s[t - off] : 0;
        __syncthreads();
        s[t] += a;
        __syncthreads();
    }
    if (t < nb) boff[t] = s[t] - v;  // exclusive
}

__global__ void scan3_kernel(int* __restrict__ rowptr, const int* __restrict__ deg_dst,
                             const int* __restrict__ boff, float* __restrict__ ndst) {
    int i = blockIdx.x * 256 + threadIdx.x;
    if (i < N_NODES) {
        int dd = deg_dst[i];
        rowptr[i] = rowptr[i] - dd + boff[blockIdx.x];
        ndst[i] = rsqrtf(fmaxf((float)dd, 1.0f));
    }
}

__global__ void fill_kernel(const int* __restrict__ src, const int* __restrict__ dst,
                            const int* __restrict__ rowptr, int* __restrict__ cursor,
                            int* __restrict__ csr, int* __restrict__ deg_src) {
    int e = blockIdx.x * blockDim.x + threadIdx.x;
    if (e < N_EDGES) {
        int s = src[e];
        int d = dst[e];
        atomicAdd(&deg_src[s], 1);
        int pos = rowptr[d] + atomicAdd(&cursor[d], 1);
        csr[pos] = s;
    }
}

__global__ void nsrc_kernel(const int* __restrict__ deg_src, float* __restrict__ nsrc) {
    int i = blockIdx.x * 256 + threadIdx.x;
    if (i < N_NODES) nsrc[i] = rsqrtf(fmaxf((float)deg_src[i], 1.0f));
}

// ---- W1 prep: split into granule order ----
__global__ void w1prep_kernel(const float* __restrict__ W1, short* __restrict__ W1S) {
    int t = blockIdx.x * 256 + threadIdx.x;  // (s*4 + k4)*128 + n
    if (t >= KSTEPS * 4 * 128) return;
    int n = t & 127;
    int k4 = (t >> 7) & 3;
    int s = t >> 9;
    long base_hi = (long)s * 8192 + ((0 * 4 + k4) * 128 + n) * 8;
    long base_lo = (long)s * 8192 + ((1 * 4 + k4) * 128 + n) * 8;
#pragma unroll
    for (int j = 0; j < 8; j++) {
        int k = s * 32 + k4 * 8 + j;
        float v = (k < F_IN) ? W1[(long)k * HID + n] : 0.f;
        short hi, lo;
        split_bf16(v, hi, lo);
        W1S[base_hi + j] = hi;
        W1S[base_lo + j] = lo;
    }
}

// ---- GEMM1 (k-split): partial = (X * nsrc) @ W1 over this block's K-slice ----
// 64x128 tile, BK=32, 4 waves 2x2. A: LDS dbuf + depth-2 X reg prefetch.
// B: single reg set per step (L2-resident W1S). One barrier/step. f32 partial out.
#define GBM 64
#define AIDX(PLANE, ROW) ((((PLANE) * 64 + (ROW)) * 8) ^ (((PLANE) & 3) << 4))

#define GEMM_BODY(EPILOGUE)                                                        \
    __shared__ __align__(16) short smem[8192];                                     \
    const int tid = threadIdx.x;                                                   \
    const int l = tid & 63;                                                        \
    const int w = tid >> 6;                                                        \
    const int wm = w >> 1, wn = w & 1;                                             \
    const int k4r = l >> 4;                                                        \
    const int l15 = l & 15;                                                        \
    const int ar = tid >> 2, ac = tid & 3;                                         \
    const int arow = bm + ar;                                                      \
    const bool ok = (arow < N_NODES);                                              \
    const float ans = ok ? nsrc[arow] : 0.f;                                       \
    const float* Xrow = X + (long)(ok ? arow : 0) * F_IN + ac * 8;                 \
    const int bg0 = (k4r * 128 + wn * 64 + l15) * 8;                               \
    f4v acc[2][4];                                                                 \
    _Pragma("unroll") for (int i = 0; i < 2; i++)                                  \
    _Pragma("unroll") for (int j = 0; j < 4; j++)                                  \
        acc[i][j] = (f4v){0.f, 0.f, 0.f, 0.f};                                     \
    float xv0[8], xv1[8];                                                          \
    s8v bfr[2][4];                                                                 \
    LOAD_X(s_begin, 0);                                                            \
    SPLIT_WRITE(0, 0);                                                             \
    LOAD_X(s_begin + 1, 0);                                                        \
    __syncthreads();                                                               \
    int s = s_begin;                                                               \
    for (; s + 1 < s_end; s += 2) {                                                \
        GITER(s, 0, 1);                                                            \
        GITER(s + 1, 1, 0);                                                        \
    }                                                                              \
    if (s < s_end) GITER(s, 0, 1);                                                 \
    EPILOGUE

#define LOAD_X(S, SET)                                                             \
    do {                                                                           \
        if ((S) != KSTEPS - 1) {                                                   \
            if (ok) {                                                              \
                float4 _a = *(const float4*)(Xrow + (S) * 32);                     \
                float4 _b = *(const float4*)(Xrow + (S) * 32 + 4);                 \
                xv##SET[0] = _a.x; xv##SET[1] = _a.y;                              \
                xv##SET[2] = _a.z; xv##SET[3] = _a.w;                              \
                xv##SET[4] = _b.x; xv##SET[5] = _b.y;                              \
                xv##SET[6] = _b.z; xv##SET[7] = _b.w;                              \
            } else {                                                               \
                for (int _j = 0; _j < 8; _j++) xv##SET[_j] = 0.f;                  \
            }                                                                      \
        } else {                                                                   \
            for (int _j = 0; _j < 8; _j++) {                                       \
                int _k = (S) * 32 + ac * 8 + _j;                                   \
                xv##SET[_j] = (ok && _k < F_IN) ? Xrow[(S) * 32 + _j] : 0.f;       \
            }                                                                      \
        }                                                                          \
    } while (0)

#define SPLIT_WRITE(SET, ABUF)                                                     \
    do {                                                                           \
        s8v _hi8, _lo8;                                                            \
        for (int _j = 0; _j < 8; _j++) {                                           \
            short _hi, _lo;                                                        \
            split_bf16_t(xv##SET[_j] * ans, _hi, _lo);                             \
            _hi8[_j] = _hi; _lo8[_j] = _lo;                                        \
        }                                                                          \
        int _base = (ABUF) * 4096;                                                 \
        *(s8v*)&smem[_base + AIDX(ac, ar)] = _hi8;                                 \
        *(s8v*)&smem[_base + AIDX(4 + ac, ar)] = _lo8;                             \
    } while (0)

#define LOAD_B(S)                                                                  \
    do {                                                                           \
        const short* _gb = W1S + (long)(S) * 8192 + bg0;                           \
        _Pragma("unroll") for (int _p = 0; _p < 2; _p++)                           \
        _Pragma("unroll") for (int _nf = 0; _nf < 4; _nf++)                        \
            bfr[_p][_nf] = *(const s8v*)(_gb + _p * 4096 + _nf * 128);             \
    } while (0)

#define GITER(S, CUR, NXT)                                                         \
    do {                                                                           \
        LOAD_B(S);                                                                 \
        if ((S) + 2 < s_end) LOAD_X((S) + 2, NXT);                                 \
        s8v _afr[2][2];                                                            \
        _Pragma("unroll") for (int _p = 0; _p < 2; _p++)                           \
        _Pragma("unroll") for (int _mf = 0; _mf < 2; _mf++)                        \
            _afr[_p][_mf] = *(const s8v*)&smem[(CUR) * 4096 +                      \
                AIDX(_p * 4 + k4r, wm * 32 + _mf * 16 + l15)];                     \
        _Pragma("unroll") for (int _mf = 0; _mf < 2; _mf++)                        \
        _Pragma("unroll") for (int _nf = 0; _nf < 4; _nf++) {                      \
            acc[_mf][_nf] = __builtin_amdgcn_mfma_f32_16x16x32_bf16(               \
                _afr[0][_mf], bfr[0][_nf], acc[_mf][_nf], 0, 0, 0);                \
            acc[_mf][_nf] = __builtin_amdgcn_mfma_f32_16x16x32_bf16(               \
                _afr[0][_mf], bfr[1][_nf], acc[_mf][_nf], 0, 0, 0);                \
            acc[_mf][_nf] = __builtin_amdgcn_mfma_f32_16x16x32_bf16(               \
                _afr[1][_mf], bfr[0][_nf], acc[_mf][_nf], 0, 0, 0);                \
        }                                                                          \
        if ((S) + 1 < s_end) {                                                     \
            SPLIT_WRITE(CUR, NXT);                                                 \
            __syncthreads();                                                       \
        }                                                                          \
    } while (0)

// k-split variant: NSPLIT blocks cooperate on one row-tile, f32 partials out
template <int NSPLIT>
__global__ __launch_bounds__(256, 4) void gemm1_split_kernel(const float* __restrict__ X,
                                                             const short* __restrict__ W1S,
                                                             const float* __restrict__ nsrc,
                                                             float* __restrict__ hp) {
    const int kb = blockIdx.x % NSPLIT;
    const int bm = (blockIdx.x / NSPLIT) * GBM;
    const int s_begin = (KSTEPS * kb + NSPLIT - 1) / NSPLIT;
    const int s_end = (KSTEPS * (kb + 1) + NSPLIT - 1) / NSPLIT;
    float* __restrict__ hpb = hp + (long)kb * HP_ELEMS;
    GEMM_BODY({
        _Pragma("unroll") for (int mf = 0; mf < 2; mf++) {
            int row0 = bm + wm * 32 + mf * 16 + (l >> 4) * 4;
            _Pragma("unroll") for (int nf = 0; nf < 4; nf++) {
                int col = wn * 64 + nf * 16 + l15;
                _Pragma("unroll") for (int r = 0; r < 4; r++) {
                    int row = row0 + r;
                    if (row < N_NODES) hpb[(long)row * HID + col] = acc[mf][nf][r];
                }
            }
        }
    })
}

// no-split fallback: fp16 out directly
__global__ __launch_bounds__(256, 4) void gemm1_mfma_kernel(const float* __restrict__ X,
                                                            const short* __restrict__ W1S,
                                                            const float* __restrict__ nsrc,
                                                            _Float16* __restrict__ h) {
    const int bm = blockIdx.x * GBM;
    const int s_begin = 0;
    const int s_end = KSTEPS;
    GEMM_BODY({
        _Pragma("unroll") for (int mf = 0; mf < 2; mf++) {
            int row0 = bm + wm * 32 + mf * 16 + (l >> 4) * 4;
            _Pragma("unroll") for (int nf = 0; nf < 4; nf++) {
                int col = wn * 64 + nf * 16 + l15;
                _Pragma("unroll") for (int r = 0; r < 4; r++) {
                    int row = row0 + r;
                    if (row < N_NODES) h[(long)row * HID + col] = (_Float16)acc[mf][nf][r];
                }
            }
        }
    })
}

// combine NSPLIT f32 partials -> fp16 h. 4 elems/thread.
template <int NSPLIT>
__global__ __launch_bounds__(256) void combine_kernel(const float* __restrict__ hp,
                                                      _Float16* __restrict__ h) {
    int i = blockIdx.x * 256 + threadIdx.x;  // quad index, total 1600000
    if (i >= HP_ELEMS / 4) return;
    float4 a = *(const float4*)(hp + (long)i * 4);
#pragma unroll
    for (int p = 1; p < NSPLIT; p++) {
        float4 b = *(const float4*)(hp + (long)p * HP_ELEMS + (long)i * 4);
        a.x += b.x; a.y += b.y; a.z += b.z; a.w += b.w;
    }
    h4v o = {(_Float16)a.x, (_Float16)a.y, (_Float16)a.z, (_Float16)a.w};
    *(h4v*)(h + (long)i * 4) = o;
}

// per dst node: agg = sum h[src] (fp16 rows), x1' = relu(agg*nd + b1)*ns, h2 = x1' @ W2
__global__ __launch_bounds__(256) void agg1_kernel(const _Float16* __restrict__ h,
                                                   const int* __restrict__ csr,
                                                   const int* __restrict__ rowptr,
                                                   const int* __restrict__ deg,
                                                   const float* __restrict__ ndst,
                                                   const float* __restrict__ nsrc,
                                                   const float* __restrict__ b1,
                                                   const float* __restrict__ W2,
                                                   float* __restrict__ h2p) {
    int wid = threadIdx.x >> 6, lane = threadIdx.x & 63;
    int node = blockIdx.x * 4 + wid;
    if (node >= N_NODES) return;
    int p = rowptr[node];
    int end = p + deg[node];
    float acc0 = 0.f, acc1 = 0.f;
    const _Float16* hb = h + 2 * lane;
    for (; p + 8 <= end; p += 8) {
        int s0 = csr[p + 0], s1 = csr[p + 1], s2 = csr[p + 2], s3 = csr[p + 3];
        int s4 = csr[p + 4], s5 = csr[p + 5], s6 = csr[p + 6], s7 = csr[p + 7];
        h2v v0 = *(const h2v*)(hb + (long)s0 * HID);
        h2v v1 = *(const h2v*)(hb + (long)s1 * HID);
        h2v v2 = *(const h2v*)(hb + (long)s2 * HID);
        h2v v3 = *(const h2v*)(hb + (long)s3 * HID);
        h2v v4 = *(const h2v*)(hb + (long)s4 * HID);
        h2v v5 = *(const h2v*)(hb + (long)s5 * HID);
        h2v v6 = *(const h2v*)(hb + (long)s6 * HID);
        h2v v7 = *(const h2v*)(hb + (long)s7 * HID);
        acc0 += (((float)v0[0] + (float)v1[0]) + ((float)v2[0] + (float)v3[0])) +
                (((float)v4[0] + (float)v5[0]) + ((float)v6[0] + (float)v7[0]));
        acc1 += (((float)v0[1] + (float)v1[1]) + ((float)v2[1] + (float)v3[1])) +
                (((float)v4[1] + (float)v5[1]) + ((float)v6[1] + (float)v7[1]));
    }
    for (; p < end; ++p) {
        int s = csr[p];
        h2v v = *(const h2v*)(hb + (long)s * HID);
        acc0 += (float)v[0];
        acc1 += (float)v[1];
    }
    float nd = ndst[node], ns = nsrc[node];
    int k0 = 2 * lane;
    float x0 = fmaxf(acc0 * nd + b1[k0], 0.f) * ns;
    float x1 = fmaxf(acc1 * nd + b1[k0 + 1], 0.f) * ns;
#pragma unroll
    for (int c = 0; c < NCLS; c++) {
        float q = x0 * W2[k0 * NCLS + c] + x1 * W2[(k0 + 1) * NCLS + c];
#pragma unroll
        for (int off = 1; off < 64; off <<= 1) q += __shfl_xor(q, off);
        if (lane == c) h2p[(long)node * 8 + c] = q;
    }
    if (lane == 7) h2p[(long)node * 8 + 7] = 0.f;
}

// per dst node: out = (sum h2[src]) * nd + b2  (h2 stride-8, 2x float4 per edge)
__global__ __launch_bounds__(256) void agg2_kernel(const float* __restrict__ h2p,
                                                   const int* __restrict__ csr,
                                                   const int* __restrict__ rowptr,
                                                   const int* __restrict__ deg,
                                                   const float* __restrict__ ndst,
                                                   const float* __restrict__ b2,
                                                   float* __restrict__ out) {
    int wid = threadIdx.x >> 6, lane = threadIdx.x & 63;
    int node = blockIdx.x * 4 + wid;
    if (node >= N_NODES) return;
    int rp = rowptr[node], end = rp + deg[node];
    float a0 = 0.f, a1 = 0.f, a2 = 0.f, a3 = 0.f, a4 = 0.f, a5 = 0.f, a6 = 0.f;
    for (int p = rp + lane; p < end; p += 64) {
        int s = csr[p];
        const float4* r = (const float4*)(h2p + (long)s * 8);
        float4 lo = r[0], hi = r[1];
        a0 += lo.x; a1 += lo.y; a2 += lo.z; a3 += lo.w;
        a4 += hi.x; a5 += hi.y; a6 += hi.z;
    }
    float nd = ndst[node];
    float acc[NCLS] = {a0, a1, a2, a3, a4, a5, a6};
#pragma unroll
    for (int c = 0; c < NCLS; c++) {
        float v = acc[c];
#pragma unroll
        for (int off = 1; off < 64; off <<= 1) v += __shfl_xor(v, off);
        if (lane == c) out[(long)node * NCLS + c] = v * nd + b2[c];
    }
}

extern "C" void kernel_launch(void* const* d_in, const int* in_sizes, int n_in,
                              void* d_out, int out_size, void* d_ws, size_t ws_size,
                              hipStream_t stream) {
    const float* X  = (const float*)d_in[0];
    const int* src  = (const int*)d_in[1];
    const int* dst  = (const int*)d_in[2];
    const float* W1 = (const float*)d_in[3];
    const float* b1 = (const float*)d_in[4];
    const float* W2 = (const float*)d_in[5];
    const float* b2 = (const float*)d_in[6];
    float* out = (float*)d_out;

    char* ws = (char*)d_ws;
    int* deg_src = (int*)(ws + O_DEG_SRC);
    int* deg_dst = (int*)(ws + O_DEG_DST);
    int* cursor  = (int*)(ws + O_CURSOR);
    int* rowptr  = (int*)(ws + O_ROWPTR);
    float* nsrc  = (float*)(ws + O_NSRC);
    float* ndst  = (float*)(ws + O_NDST);
    int* bsum    = (int*)(ws + O_BSUM);
    int* boff    = (int*)(ws + O_BOFF);
    int* csr     = (int*)(ws + O_CSR);
    _Float16* h  = (_Float16*)(ws + O_H);
    float* h2p   = (float*)(ws + O_H2);
    short* W1S   = (short*)(ws + O_W1S);
    float* hp    = (float*)(ws + O_HP0);

    const int nb = (N_NODES + 255) / 256;  // 196
    const int gblocks = (N_NODES + GBM - 1) / GBM;  // 782
    zero_ws_kernel<<<147, 256, 0, stream>>>((int4*)ws);
    w1prep_kernel<<<(KSTEPS * 4 * 128 + 255) / 256, 256, 0, stream>>>(W1, W1S);
    deg_kernel<<<N_EDGES / 256, 256, 0, stream>>>(dst, deg_dst);
    scan1_kernel<<<nb, 256, 0, stream>>>(deg_dst, rowptr, bsum);
    scan2_kernel<<<1, 256, 0, stream>>>(bsum, boff, nb);
    scan3_kernel<<<nb, 256, 0, stream>>>(rowptr, deg_dst, boff, ndst);
    fill_kernel<<<N_EDGES / 256, 256, 0, stream>>>(src, dst, rowptr, cursor, csr, deg_src);
    nsrc_kernel<<<nb, 256, 0, stream>>>(deg_src, nsrc);

    const int cb = (HP_ELEMS / 4 + 255) / 256;  // 6250
    if (ws_size >= (size_t)O_HP0 + 4ull * HP_ELEMS * 4) {
        gemm1_split_kernel<4><<<gblocks * 4, 256, 0, stream>>>(X, W1S, nsrc, hp);
        combine_kernel<4><<<cb, 256, 0, stream>>>(hp, h);
    } else if (ws_size >= (size_t)O_HP0 + 2ull * HP_ELEMS * 4) {
        gemm1_split_kernel<2><<<gblocks * 2, 256, 0, stream>>>(X, W1S, nsrc, hp);
        combine_kernel<2><<<cb, 256, 0, stream>>>(hp, h);
    } else {
        gemm1_mfma_kernel<<<gblocks, 256, 0, stream>>>(X, W1S, nsrc, h);
    }

    agg1_kernel<<<(N_NODES + 3) / 4, 256, 0, stream>>>(h, csr, rowptr, deg_dst, ndst, nsrc,
                                                       b1, W2, h2p);
    agg2_kernel<<<(N_NODES + 3) / 4, 256, 0, stream>>>(h2p, csr, rowptr, deg_dst, ndst, b2, out);
}

// Round 13
// 437.588 us; speedup vs baseline: 1.1145x; 1.1145x over previous
//
#include <hip/hip_runtime.h>

#define N_NODES 50000
#define N_EDGES 1600000
#define F_IN 1433
#define HID 128
#define NCLS 7
#define KSTEPS 45

// ---- workspace layout (bytes), all 256-aligned ----
#define O_DEG_SRC 0u          // N ints   (200000)
#define O_DEG_DST 200704u     // N ints
#define O_CURSOR  401408u     // N ints
#define O_ROWPTR  602112u     // N+1 ints
#define O_NSRC    802816u     // N floats
#define O_NDST    1003520u    // N floats
#define O_BSUM    1204224u    // 256 ints
#define O_BOFF    1205248u    // 256 ints
#define O_CSR     1206272u    // E ints (6400000)
#define O_H       7606272u    // N*128 _Float16 (12800000), 16B aligned
#define O_H2      33206272u   // N*8 floats padded (1600000)
#define O_W1S     34806272u   // 45*2*4*128*8 shorts = 737280 B

typedef __attribute__((ext_vector_type(8))) short s8v;       // 8 bf16 (4 VGPRs)
typedef __attribute__((ext_vector_type(4))) float f4v;       // 4 f32
typedef __attribute__((ext_vector_type(8))) _Float16 h8v;    // 8 fp16 (16B)

// RNE f32 -> bf16 hi, residual -> bf16 lo (RNE, used for W1 prep)
__device__ __forceinline__ void split_bf16(float v, short& hi, short& lo) {
    unsigned u = __builtin_bit_cast(unsigned, v);
    unsigned r = u + 0x7FFFu + ((u >> 16) & 1u);
    unsigned short h = (unsigned short)(r >> 16);
    float hf = __builtin_bit_cast(float, (unsigned)h << 16);
    float lv = v - hf;
    unsigned u2 = __builtin_bit_cast(unsigned, lv);
    unsigned r2 = u2 + 0x7FFFu + ((u2 >> 16) & 1u);
    hi = (short)h;
    lo = (short)(r2 >> 16);
}

// cheaper variant for the per-step A split: lo truncated
__device__ __forceinline__ void split_bf16_t(float v, short& hi, short& lo) {
    unsigned u = __builtin_bit_cast(unsigned, v);
    unsigned r = u + 0x7FFFu + ((u >> 16) & 1u);
    unsigned short h = (unsigned short)(r >> 16);
    float hf = __builtin_bit_cast(float, (unsigned)h << 16);
    float lv = v - hf;
    hi = (short)h;
    lo = (short)(__builtin_bit_cast(unsigned, lv) >> 16);
}

__global__ void zero_ws_kernel(int4* __restrict__ p) {
    int i = blockIdx.x * 256 + threadIdx.x;
    if (i < 37632) p[i] = make_int4(0, 0, 0, 0);
}

__global__ void deg_kernel(const int* __restrict__ dst, int* __restrict__ deg_dst) {
    int e = blockIdx.x * blockDim.x + threadIdx.x;
    if (e < N_EDGES) atomicAdd(&deg_dst[dst[e]], 1);
}

__global__ void scan1_kernel(const int* __restrict__ deg, int* __restrict__ incl,
                             int* __restrict__ bsum) {
    __shared__ int s[256];
    int t = threadIdx.x;
    int i = blockIdx.x * 256 + t;
    int v = (i < N_NODES) ? deg[i] : 0;
    s[t] = v;
    __syncthreads();
    for (int off = 1; off < 256; off <<= 1) {
        int a = (t >= off) ? s[t - off] : 0;
        __syncthreads();
        s[t] += a;
        __syncthreads();
    }
    if (i < N_NODES) incl[i] = s[t];
    if (t == 255) bsum[blockIdx.x] = s[255];
}

__global__ void scan2_kernel(const int* __restrict__ bsum, int* __restrict__ boff, int nb) {
    __shared__ int s[256];
    int t = threadIdx.x;
    int v = (t < nb) ? bsum[t] : 0;
    s[t] = v;
    __syncthreads();
    for (int off = 1; off < 256; off <<= 1) {
        int a = (t >= off) ? s[t - off] : 0;
        __syncthreads();
        s[t] += a;
        __syncthreads();
    }
    if (t < nb) boff[t] = s[t] - v;  // exclusive
}

__global__ void scan3_kernel(int* __restrict__ rowptr, const int* __restrict__ deg_dst,
                             const int* __restrict__ boff, float* __restrict__ ndst) {
    int i = blockIdx.x * 256 + threadIdx.x;
    if (i < N_NODES) {
        int dd = deg_dst[i];
        rowptr[i] = rowptr[i] - dd + boff[blockIdx.x];
        ndst[i] = rsqrtf(fmaxf((float)dd, 1.0f));
    }
}

__global__ void fill_kernel(const int* __restrict__ src, const int* __restrict__ dst,
                            const int* __restrict__ rowptr, int* __restrict__ cursor,
                            int* __restrict__ csr, int* __restrict__ deg_src) {
    int e = blockIdx.x * blockDim.x + threadIdx.x;
    if (e < N_EDGES) {
        int s = src[e];
        int d = dst[e];
        atomicAdd(&deg_src[s], 1);
        int pos = rowptr[d] + atomicAdd(&cursor[d], 1);
        csr[pos] = s;
    }
}

__global__ void nsrc_kernel(const int* __restrict__ deg_src, float* __restrict__ nsrc) {
    int i = blockIdx.x * 256 + threadIdx.x;
    if (i < N_NODES) nsrc[i] = rsqrtf(fmaxf((float)deg_src[i], 1.0f));
}

// ---- W1 prep: split into granule order ----
__global__ void w1prep_kernel(const float* __restrict__ W1, short* __restrict__ W1S) {
    int t = blockIdx.x * 256 + threadIdx.x;  // (s*4 + k4)*128 + n
    if (t >= KSTEPS * 4 * 128) return;
    int n = t & 127;
    int k4 = (t >> 7) & 3;
    int s = t >> 9;
    long base_hi = (long)s * 8192 + ((0 * 4 + k4) * 128 + n) * 8;
    long base_lo = (long)s * 8192 + ((1 * 4 + k4) * 128 + n) * 8;
#pragma unroll
    for (int j = 0; j < 8; j++) {
        int k = s * 32 + k4 * 8 + j;
        float v = (k < F_IN) ? W1[(long)k * HID + n] : 0.f;
        short hi, lo;
        split_bf16(v, hi, lo);
        W1S[base_hi + j] = hi;
        W1S[base_lo + j] = lo;
    }
}

// ---- GEMM1: h = (X * nsrc[:,None]) @ W1, bf16 hi/lo split MFMA, fp16 out ----
// r8/r11 structure (best measured): 64x128 tile, BK=32, 4 waves 2x2.
// A: LDS dbuf + depth-2 X reg prefetch; B: single reg set/step; 1 barrier/step.
#define GBM 64
#define AIDX(PLANE, ROW) ((((PLANE) * 64 + (ROW)) * 8) ^ (((PLANE) & 3) << 4))
__global__ __launch_bounds__(256, 4) void gemm1_mfma_kernel(const float* __restrict__ X,
                                                            const short* __restrict__ W1S,
                                                            const float* __restrict__ nsrc,
                                                            _Float16* __restrict__ h) {
    __shared__ __align__(16) short smem[8192];
    const int tid = threadIdx.x;
    const int l = tid & 63;
    const int w = tid >> 6;
    const int wm = w >> 1, wn = w & 1;
    const int k4r = l >> 4;
    const int l15 = l & 15;
    const int bm = blockIdx.x * GBM;

    const int ar = tid >> 2, ac = tid & 3;
    const int arow = bm + ar;
    const bool ok = (arow < N_NODES);
    const float ans = ok ? nsrc[arow] : 0.f;
    const float* Xrow = X + (long)(ok ? arow : 0) * F_IN + ac * 8;

    const int bg0 = (k4r * 128 + wn * 64 + l15) * 8;

    f4v acc[2][4];
#pragma unroll
    for (int i = 0; i < 2; i++)
#pragma unroll
        for (int j = 0; j < 4; j++) acc[i][j] = (f4v){0.f, 0.f, 0.f, 0.f};

    float xv0[8], xv1[8];
    s8v bfr[2][4];

#define LOAD_X(S, SET)                                                             \
    do {                                                                           \
        if ((S) != KSTEPS - 1) {                                                   \
            if (ok) {                                                              \
                float4 _a = *(const float4*)(Xrow + (S) * 32);                     \
                float4 _b = *(const float4*)(Xrow + (S) * 32 + 4);                 \
                xv##SET[0] = _a.x; xv##SET[1] = _a.y;                              \
                xv##SET[2] = _a.z; xv##SET[3] = _a.w;                              \
                xv##SET[4] = _b.x; xv##SET[5] = _b.y;                              \
                xv##SET[6] = _b.z; xv##SET[7] = _b.w;                              \
            } else {                                                               \
                for (int _j = 0; _j < 8; _j++) xv##SET[_j] = 0.f;                  \
            }                                                                      \
        } else {                                                                   \
            for (int _j = 0; _j < 8; _j++) {                                       \
                int _k = (S) * 32 + ac * 8 + _j;                                   \
                xv##SET[_j] = (ok && _k < F_IN) ? Xrow[(S) * 32 + _j] : 0.f;       \
            }                                                                      \
        }                                                                          \
    } while (0)

#define SPLIT_WRITE(SET, ABUF)                                                     \
    do {                                                                           \
        s8v _hi8, _lo8;                                                            \
        for (int _j = 0; _j < 8; _j++) {                                           \
            short _hi, _lo;                                                        \
            split_bf16_t(xv##SET[_j] * ans, _hi, _lo);                             \
            _hi8[_j] = _hi; _lo8[_j] = _lo;                                        \
        }                                                                          \
        int _base = (ABUF) * 4096;                                                 \
        *(s8v*)&smem[_base + AIDX(ac, ar)] = _hi8;                                 \
        *(s8v*)&smem[_base + AIDX(4 + ac, ar)] = _lo8;                             \
    } while (0)

#define LOAD_B(S)                                                                  \
    do {                                                                           \
        const short* _gb = W1S + (long)(S) * 8192 + bg0;                           \
        _Pragma("unroll") for (int _p = 0; _p < 2; _p++)                           \
        _Pragma("unroll") for (int _nf = 0; _nf < 4; _nf++)                        \
            bfr[_p][_nf] = *(const s8v*)(_gb + _p * 4096 + _nf * 128);             \
    } while (0)

#define GITER(S, CUR, NXT)                                                         \
    do {                                                                           \
        LOAD_B(S);                                                                 \
        if ((S) + 2 < KSTEPS) LOAD_X((S) + 2, NXT);                                \
        s8v _afr[2][2];                                                            \
        _Pragma("unroll") for (int _p = 0; _p < 2; _p++)                           \
        _Pragma("unroll") for (int _mf = 0; _mf < 2; _mf++)                        \
            _afr[_p][_mf] = *(const s8v*)&smem[(CUR) * 4096 +                      \
                AIDX(_p * 4 + k4r, wm * 32 + _mf * 16 + l15)];                     \
        _Pragma("unroll") for (int _mf = 0; _mf < 2; _mf++)                        \
        _Pragma("unroll") for (int _nf = 0; _nf < 4; _nf++) {                      \
            acc[_mf][_nf] = __builtin_amdgcn_mfma_f32_16x16x32_bf16(               \
                _afr[0][_mf], bfr[0][_nf], acc[_mf][_nf], 0, 0, 0);                \
            acc[_mf][_nf] = __builtin_amdgcn_mfma_f32_16x16x32_bf16(               \
                _afr[0][_mf], bfr[1][_nf], acc[_mf][_nf], 0, 0, 0);                \
            acc[_mf][_nf] = __builtin_amdgcn_mfma_f32_16x16x32_bf16(               \
                _afr[1][_mf], bfr[0][_nf], acc[_mf][_nf], 0, 0, 0);                \
        }                                                                          \
        if ((S) + 1 < KSTEPS) {                                                    \
            SPLIT_WRITE(CUR, NXT);                                                 \
            __syncthreads();                                                       \
        }                                                                          \
    } while (0)

    LOAD_X(0, 0);
    SPLIT_WRITE(0, 0);
    LOAD_X(1, 0);
    __syncthreads();

    for (int s = 0; s + 1 < KSTEPS; s += 2) {
        GITER(s, 0, 1);
        GITER(s + 1, 1, 0);
    }
    GITER(KSTEPS - 1, 0, 1);

#pragma unroll
    for (int mf = 0; mf < 2; mf++) {
        int row0 = bm + wm * 32 + mf * 16 + (l >> 4) * 4;
#pragma unroll
        for (int nf = 0; nf < 4; nf++) {
            int col = wn * 64 + nf * 16 + l15;
#pragma unroll
            for (int r = 0; r < 4; r++) {
                int row = row0 + r;
                if (row < N_NODES) h[(long)row * HID + col] = (_Float16)acc[mf][nf][r];
            }
        }
    }
#undef LOAD_X
#undef SPLIT_WRITE
#undef LOAD_B
#undef GITER
}

// ---- agg1: 16-lane group per node, 4 rows per wave-load ----
// group g of each wave owns node (blk*16 + wave*4 + g); lane fl = lane&15 holds
// features fl*8..fl*8+8 (16B = one h8v). One load instr fetches 4 different
// nodes' rows at once; x4 unroll -> 16 rows in flight per wave.
__global__ __launch_bounds__(256) void agg1_kernel(const _Float16* __restrict__ h,
                                                   const int* __restrict__ csr,
                                                   const int* __restrict__ rowptr,
                                                   const int* __restrict__ deg,
                                                   const float* __restrict__ ndst,
                                                   const float* __restrict__ nsrc,
                                                   const float* __restrict__ b1,
                                                   const float* __restrict__ W2,
                                                   float* __restrict__ h2p) {
    const int lane = threadIdx.x & 63;
    const int wave = threadIdx.x >> 6;
    const int fl = lane & 15;
    const int node = blockIdx.x * 16 + wave * 4 + (lane >> 4);
    const bool active = node < N_NODES;
    int p = active ? rowptr[node] : 0;
    int end = active ? p + deg[node] : 0;

    float acc[8];
#pragma unroll
    for (int j = 0; j < 8; j++) acc[j] = 0.f;
    const _Float16* hb = h + fl * 8;

    // unroll-4: 4 independent row loads per group in flight
    for (; p + 4 <= end; p += 4) {
        int i0 = csr[p], i1 = csr[p + 1], i2 = csr[p + 2], i3 = csr[p + 3];
        h8v a0 = *(const h8v*)(hb + (long)i0 * HID);
        h8v a1 = *(const h8v*)(hb + (long)i1 * HID);
        h8v a2 = *(const h8v*)(hb + (long)i2 * HID);
        h8v a3 = *(const h8v*)(hb + (long)i3 * HID);
#pragma unroll
        for (int j = 0; j < 8; j++)
            acc[j] += ((float)a0[j] + (float)a1[j]) + ((float)a2[j] + (float)a3[j]);
    }
    for (; p < end; ++p) {
        int i0 = csr[p];
        h8v a0 = *(const h8v*)(hb + (long)i0 * HID);
#pragma unroll
        for (int j = 0; j < 8; j++) acc[j] += (float)a0[j];
    }

    float nd = active ? ndst[node] : 0.f;
    float ns = active ? nsrc[node] : 0.f;
    float x[8];
#pragma unroll
    for (int j = 0; j < 8; j++)
        x[j] = fmaxf(acc[j] * nd + b1[fl * 8 + j], 0.f) * ns;

    float q[NCLS];
#pragma unroll
    for (int c = 0; c < NCLS; c++) {
        float s = 0.f;
#pragma unroll
        for (int j = 0; j < 8; j++) s += x[j] * W2[(fl * 8 + j) * NCLS + c];
        q[c] = s;
    }
    // reduce across the 16 lanes of the group
#pragma unroll
    for (int c = 0; c < NCLS; c++) {
#pragma unroll
        for (int off = 1; off < 16; off <<= 1) q[c] += __shfl_xor(q[c], off);
    }
    if (active) {
        if (fl < NCLS) h2p[(long)node * 8 + fl] = q[fl];
        if (fl == 7) h2p[(long)node * 8 + 7] = 0.f;
    }
}

// per dst node: out = (sum h2[src]) * nd + b2  (h2 stride-8, 2x float4 per edge)
__global__ __launch_bounds__(256) void agg2_kernel(const float* __restrict__ h2p,
                                                   const int* __restrict__ csr,
                                                   const int* __restrict__ rowptr,
                                                   const int* __restrict__ deg,
                                                   const float* __restrict__ ndst,
                                                   const float* __restrict__ b2,
                                                   float* __restrict__ out) {
    int wid = threadIdx.x >> 6, lane = threadIdx.x & 63;
    int node = blockIdx.x * 4 + wid;
    if (node >= N_NODES) return;
    int rp = rowptr[node], end = rp + deg[node];
    float a0 = 0.f, a1 = 0.f, a2 = 0.f, a3 = 0.f, a4 = 0.f, a5 = 0.f, a6 = 0.f;
    for (int p = rp + lane; p < end; p += 64) {
        int s = csr[p];
        const float4* r = (const float4*)(h2p + (long)s * 8);
        float4 lo = r[0], hi = r[1];
        a0 += lo.x; a1 += lo.y; a2 += lo.z; a3 += lo.w;
        a4 += hi.x; a5 += hi.y; a6 += hi.z;
    }
    float nd = ndst[node];
    float acc[NCLS] = {a0, a1, a2, a3, a4, a5, a6};
#pragma unroll
    for (int c = 0; c < NCLS; c++) {
        float v = acc[c];
#pragma unroll
        for (int off = 1; off < 64; off <<= 1) v += __shfl_xor(v, off);
        if (lane == c) out[(long)node * NCLS + c] = v * nd + b2[c];
    }
}

extern "C" void kernel_launch(void* const* d_in, const int* in_sizes, int n_in,
                              void* d_out, int out_size, void* d_ws, size_t ws_size,
                              hipStream_t stream) {
    const float* X  = (const float*)d_in[0];
    const int* src  = (const int*)d_in[1];
    const int* dst  = (const int*)d_in[2];
    const float* W1 = (const float*)d_in[3];
    const float* b1 = (const float*)d_in[4];
    const float* W2 = (const float*)d_in[5];
    const float* b2 = (const float*)d_in[6];
    float* out = (float*)d_out;

    char* ws = (char*)d_ws;
    int* deg_src = (int*)(ws + O_DEG_SRC);
    int* deg_dst = (int*)(ws + O_DEG_DST);
    int* cursor  = (int*)(ws + O_CURSOR);
    int* rowptr  = (int*)(ws + O_ROWPTR);
    float* nsrc  = (float*)(ws + O_NSRC);
    float* ndst  = (float*)(ws + O_NDST);
    int* bsum    = (int*)(ws + O_BSUM);
    int* boff    = (int*)(ws + O_BOFF);
    int* csr     = (int*)(ws + O_CSR);
    _Float16* h  = (_Float16*)(ws + O_H);
    float* h2p   = (float*)(ws + O_H2);
    short* W1S   = (short*)(ws + O_W1S);

    const int nb = (N_NODES + 255) / 256;  // 196
    zero_ws_kernel<<<147, 256, 0, stream>>>((int4*)ws);
    w1prep_kernel<<<(KSTEPS * 4 * 128 + 255) / 256, 256, 0, stream>>>(W1, W1S);
    deg_kernel<<<N_EDGES / 256, 256, 0, stream>>>(dst, deg_dst);
    scan1_kernel<<<nb, 256, 0, stream>>>(deg_dst, rowptr, bsum);
    scan2_kernel<<<1, 256, 0, stream>>>(bsum, boff, nb);
    scan3_kernel<<<nb, 256, 0, stream>>>(rowptr, deg_dst, boff, ndst);
    fill_kernel<<<N_EDGES / 256, 256, 0, stream>>>(src, dst, rowptr, cursor, csr, deg_src);
    nsrc_kernel<<<nb, 256, 0, stream>>>(deg_src, nsrc);

    gemm1_mfma_kernel<<<(N_NODES + GBM - 1) / GBM, 256, 0, stream>>>(X, W1S, nsrc, h);

    agg1_kernel<<<(N_NODES + 15) / 16, 256, 0, stream>>>(h, csr, rowptr, deg_dst, ndst, nsrc,
                                                         b1, W2, h2p);
    agg2_kernel<<<(N_NODES + 3) / 4, 256, 0, stream>>>(h2p, csr, rowptr, deg_dst, ndst, b2, out);
}

// Round 14
// 432.471 us; speedup vs baseline: 1.1277x; 1.0118x over previous
//
#include <hip/hip_runtime.h>

#define N_NODES 50000
#define N_EDGES 1600000
#define F_IN 1433
#define HID 128
#define NCLS 7
#define KSTEPS 45

// ---- workspace layout (bytes), all 256-aligned ----
#define O_DEG_SRC 0u          // N ints   (200000)
#define O_DEG_DST 200704u     // N ints
#define O_CURSOR  401408u     // N ints
#define O_ROWPTR  602112u     // N+1 ints
#define O_NSRC    802816u     // N floats
#define O_NDST    1003520u    // N floats
#define O_BSUM    1204224u    // 256 ints
#define O_BOFF    1205248u    // 256 ints
#define O_CSR     1206272u    // E ints (6400000)
#define O_H       7606272u    // N*128 _Float16 (12800000), 16B aligned
#define O_H2      33206272u   // N*8 floats padded (1600000)
#define O_W1S     34806272u   // 45*4096 _Float16 = 368640 B (fp16, staged layout)

typedef __attribute__((ext_vector_type(4))) float f4v;       // 4 f32
typedef __attribute__((ext_vector_type(8))) _Float16 h8v;    // 8 fp16 (16B, 4 VGPRs)

__global__ void zero_ws_kernel(int4* __restrict__ p) {
    int i = blockIdx.x * 256 + threadIdx.x;
    if (i < 37632) p[i] = make_int4(0, 0, 0, 0);
}

__global__ void deg_kernel(const int* __restrict__ dst, int* __restrict__ deg_dst) {
    int e = blockIdx.x * blockDim.x + threadIdx.x;
    if (e < N_EDGES) atomicAdd(&deg_dst[dst[e]], 1);
}

__global__ void scan1_kernel(const int* __restrict__ deg, int* __restrict__ incl,
                             int* __restrict__ bsum) {
    __shared__ int s[256];
    int t = threadIdx.x;
    int i = blockIdx.x * 256 + t;
    int v = (i < N_NODES) ? deg[i] : 0;
    s[t] = v;
    __syncthreads();
    for (int off = 1; off < 256; off <<= 1) {
        int a = (t >= off) ? s[t - off] : 0;
        __syncthreads();
        s[t] += a;
        __syncthreads();
    }
    if (i < N_NODES) incl[i] = s[t];
    if (t == 255) bsum[blockIdx.x] = s[255];
}

__global__ void scan2_kernel(const int* __restrict__ bsum, int* __restrict__ boff, int nb) {
    __shared__ int s[256];
    int t = threadIdx.x;
    int v = (t < nb) ? bsum[t] : 0;
    s[t] = v;
    __syncthreads();
    for (int off = 1; off < 256; off <<= 1) {
        int a = (t >= off) ? s[t - off] : 0;
        __syncthreads();
        s[t] += a;
        __syncthreads();
    }
    if (t < nb) boff[t] = s[t] - v;  // exclusive
}

__global__ void scan3_kernel(int* __restrict__ rowptr, const int* __restrict__ deg_dst,
                             const int* __restrict__ boff, float* __restrict__ ndst) {
    int i = blockIdx.x * 256 + threadIdx.x;
    if (i < N_NODES) {
        int dd = deg_dst[i];
        rowptr[i] = rowptr[i] - dd + boff[blockIdx.x];
        ndst[i] = rsqrtf(fmaxf((float)dd, 1.0f));
    }
}

__global__ void fill_kernel(const int* __restrict__ src, const int* __restrict__ dst,
                            const int* __restrict__ rowptr, int* __restrict__ cursor,
                            int* __restrict__ csr, int* __restrict__ deg_src) {
    int e = blockIdx.x * blockDim.x + threadIdx.x;
    if (e < N_EDGES) {
        int s = src[e];
        int d = dst[e];
        atomicAdd(&deg_src[s], 1);
        int pos = rowptr[d] + atomicAdd(&cursor[d], 1);
        csr[pos] = s;
    }
}

__global__ void nsrc_kernel(const int* __restrict__ deg_src, float* __restrict__ nsrc) {
    int i = blockIdx.x * 256 + threadIdx.x;
    if (i < N_NODES) nsrc[i] = rsqrtf(fmaxf((float)deg_src[i], 1.0f));
}

// ---- W1 prep: fp16, staged granule order ----
// W1S[s*4096 + (k4*128 + n)*8 + j] = (fp16) W1[s*32 + k4*8 + j][n], zero-pad k>=F_IN
__global__ void w1prep_kernel(const float* __restrict__ W1, _Float16* __restrict__ W1S) {
    int t = blockIdx.x * 256 + threadIdx.x;  // (s*4 + k4)*128 + n, total 23040
    if (t >= KSTEPS * 4 * 128) return;
    int n = t & 127;
    int k4 = (t >> 7) & 3;
    int s = t >> 9;
    long base = (long)s * 4096 + (k4 * 128 + n) * 8;
#pragma unroll
    for (int j = 0; j < 8; j++) {
        int k = s * 32 + k4 * 8 + j;
        W1S[base + j] = (_Float16)((k < F_IN) ? W1[(long)k * HID + n] : 0.f);
    }
}

// ---- GEMM1: h = (X * nsrc[:,None]) @ W1, single fp16 MFMA, fp16 out ----
// 64x128 tile, BK=32, 4 waves 2x2 (wave tile 32x64). 8 MFMA/step.
// A: LDS dbuf (8 KB) + depth-2 X reg prefetch; B: single reg set/step (4KB/wave);
// 1 barrier/step.
#define GBM 64
__global__ __launch_bounds__(256, 4) void gemm1_mfma_kernel(const float* __restrict__ X,
                                                            const _Float16* __restrict__ W1S,
                                                            const float* __restrict__ nsrc,
                                                            _Float16* __restrict__ h) {
    // A plane layout per buffer: [k4 0..3][row 0..63][8 fp16]; 2048 elems/buffer
    __shared__ __align__(16) _Float16 smem[4096];
    const int tid = threadIdx.x;
    const int l = tid & 63;
    const int w = tid >> 6;
    const int wm = w >> 1, wn = w & 1;
    const int k4r = l >> 4;
    const int l15 = l & 15;
    const int bm = blockIdx.x * GBM;

    const int ar = tid >> 2, ac = tid & 3;
    const int arow = bm + ar;
    const bool ok = (arow < N_NODES);
    const float ans = ok ? nsrc[arow] : 0.f;
    const float* Xrow = X + (long)(ok ? arow : 0) * F_IN + ac * 8;

    // per-lane B granule offset within one step's 4096-elem panel
    const int bg0 = (k4r * 128 + wn * 64 + l15) * 8;  // + nf*128

    f4v acc[2][4];
#pragma unroll
    for (int i = 0; i < 2; i++)
#pragma unroll
        for (int j = 0; j < 4; j++) acc[i][j] = (f4v){0.f, 0.f, 0.f, 0.f};

    float xv0[8], xv1[8];
    h8v bfr[4];

#define LOAD_X(S, SET)                                                             \
    do {                                                                           \
        if ((S) != KSTEPS - 1) {                                                   \
            if (ok) {                                                              \
                float4 _a = *(const float4*)(Xrow + (S) * 32);                     \
                float4 _b = *(const float4*)(Xrow + (S) * 32 + 4);                 \
                xv##SET[0] = _a.x; xv##SET[1] = _a.y;                              \
                xv##SET[2] = _a.z; xv##SET[3] = _a.w;                              \
                xv##SET[4] = _b.x; xv##SET[5] = _b.y;                              \
                xv##SET[6] = _b.z; xv##SET[7] = _b.w;                              \
            } else {                                                               \
                for (int _j = 0; _j < 8; _j++) xv##SET[_j] = 0.f;                  \
            }                                                                      \
        } else {                                                                   \
            for (int _j = 0; _j < 8; _j++) {                                       \
                int _k = (S) * 32 + ac * 8 + _j;                                   \
                xv##SET[_j] = (ok && _k < F_IN) ? Xrow[(S) * 32 + _j] : 0.f;       \
            }                                                                      \
        }                                                                          \
    } while (0)

#define SPLIT_WRITE(SET, ABUF)                                                     \
    do {                                                                           \
        h8v _v;                                                                    \
        for (int _j = 0; _j < 8; _j++) _v[_j] = (_Float16)(xv##SET[_j] * ans);     \
        *(h8v*)&smem[(ABUF) * 2048 + (ac * 64 + ar) * 8] = _v;                     \
    } while (0)

#define LOAD_B(S)                                                                  \
    do {                                                                           \
        const _Float16* _gb = W1S + (long)(S) * 4096 + bg0;                        \
        _Pragma("unroll") for (int _nf = 0; _nf < 4; _nf++)                        \
            bfr[_nf] = *(const h8v*)(_gb + _nf * 128);                             \
    } while (0)

// entry invariant: A(S) staged in buf CUR; xv##CUR holds X(S+1)
#define GITER(S, CUR, NXT)                                                         \
    do {                                                                           \
        LOAD_B(S);                                                                 \
        if ((S) + 2 < KSTEPS) LOAD_X((S) + 2, NXT);                                \
        h8v _afr[2];                                                               \
        _Pragma("unroll") for (int _mf = 0; _mf < 2; _mf++)                        \
            _afr[_mf] = *(const h8v*)&smem[(CUR) * 2048 +                          \
                (k4r * 64 + wm * 32 + _mf * 16 + l15) * 8];                        \
        _Pragma("unroll") for (int _mf = 0; _mf < 2; _mf++)                        \
        _Pragma("unroll") for (int _nf = 0; _nf < 4; _nf++)                        \
            acc[_mf][_nf] = __builtin_amdgcn_mfma_f32_16x16x32_f16(                \
                _afr[_mf], bfr[_nf], acc[_mf][_nf], 0, 0, 0);                      \
        if ((S) + 1 < KSTEPS) {                                                    \
            SPLIT_WRITE(CUR, NXT);                                                 \
            __syncthreads();                                                       \
        }                                                                          \
    } while (0)

    // prologue: A(0) -> buf0; xv0 := X(1)
    LOAD_X(0, 0);
    SPLIT_WRITE(0, 0);
    LOAD_X(1, 0);
    __syncthreads();

    for (int s = 0; s + 1 < KSTEPS; s += 2) {
        GITER(s, 0, 1);
        GITER(s + 1, 1, 0);
    }
    GITER(KSTEPS - 1, 0, 1);

    // epilogue: D frag row=(l>>4)*4+reg, col=l&15; convert to fp16
#pragma unroll
    for (int mf = 0; mf < 2; mf++) {
        int row0 = bm + wm * 32 + mf * 16 + (l >> 4) * 4;
#pragma unroll
        for (int nf = 0; nf < 4; nf++) {
            int col = wn * 64 + nf * 16 + l15;
#pragma unroll
            for (int r = 0; r < 4; r++) {
                int row = row0 + r;
                if (row < N_NODES) h[(long)row * HID + col] = (_Float16)acc[mf][nf][r];
            }
        }
    }
#undef LOAD_X
#undef SPLIT_WRITE
#undef LOAD_B
#undef GITER
}

// ---- agg1: 16-lane group per node, 4 rows per wave-load, unroll 8 ----
__global__ __launch_bounds__(256) void agg1_kernel(const _Float16* __restrict__ h,
                                                   const int* __restrict__ csr,
                                                   const int* __restrict__ rowptr,
                                                   const int* __restrict__ deg,
                                                   const float* __restrict__ ndst,
                                                   const float* __restrict__ nsrc,
                                                   const float* __restrict__ b1,
                                                   const float* __restrict__ W2,
                                                   float* __restrict__ h2p) {
    const int lane = threadIdx.x & 63;
    const int wave = threadIdx.x >> 6;
    const int fl = lane & 15;
    const int node = blockIdx.x * 16 + wave * 4 + (lane >> 4);
    const bool active = node < N_NODES;
    int p = active ? rowptr[node] : 0;
    int end = active ? p + deg[node] : 0;

    float acc[8];
#pragma unroll
    for (int j = 0; j < 8; j++) acc[j] = 0.f;
    const _Float16* hb = h + fl * 8;

    // unroll-8: 8 independent row loads per group in flight (32 rows/wave)
    for (; p + 8 <= end; p += 8) {
        int i0 = csr[p], i1 = csr[p + 1], i2 = csr[p + 2], i3 = csr[p + 3];
        int i4 = csr[p + 4], i5 = csr[p + 5], i6 = csr[p + 6], i7 = csr[p + 7];
        h8v a0 = *(const h8v*)(hb + (long)i0 * HID);
        h8v a1 = *(const h8v*)(hb + (long)i1 * HID);
        h8v a2 = *(const h8v*)(hb + (long)i2 * HID);
        h8v a3 = *(const h8v*)(hb + (long)i3 * HID);
        h8v a4 = *(const h8v*)(hb + (long)i4 * HID);
        h8v a5 = *(const h8v*)(hb + (long)i5 * HID);
        h8v a6 = *(const h8v*)(hb + (long)i6 * HID);
        h8v a7 = *(const h8v*)(hb + (long)i7 * HID);
#pragma unroll
        for (int j = 0; j < 8; j++)
            acc[j] += (((float)a0[j] + (float)a1[j]) + ((float)a2[j] + (float)a3[j])) +
                      (((float)a4[j] + (float)a5[j]) + ((float)a6[j] + (float)a7[j]));
    }
    for (; p < end; ++p) {
        int i0 = csr[p];
        h8v a0 = *(const h8v*)(hb + (long)i0 * HID);
#pragma unroll
        for (int j = 0; j < 8; j++) acc[j] += (float)a0[j];
    }

    float nd = active ? ndst[node] : 0.f;
    float ns = active ? nsrc[node] : 0.f;
    float x[8];
#pragma unroll
    for (int j = 0; j < 8; j++)
        x[j] = fmaxf(acc[j] * nd + b1[fl * 8 + j], 0.f) * ns;

    float q[NCLS];
#pragma unroll
    for (int c = 0; c < NCLS; c++) {
        float s = 0.f;
#pragma unroll
        for (int j = 0; j < 8; j++) s += x[j] * W2[(fl * 8 + j) * NCLS + c];
        q[c] = s;
    }
#pragma unroll
    for (int c = 0; c < NCLS; c++) {
#pragma unroll
        for (int off = 1; off < 16; off <<= 1) q[c] += __shfl_xor(q[c], off);
    }
    if (active) {
        if (fl < NCLS) h2p[(long)node * 8 + fl] = q[fl];
        if (fl == 7) h2p[(long)node * 8 + 7] = 0.f;
    }
}

// per dst node: out = (sum h2[src]) * nd + b2  (h2 stride-8, 2x float4 per edge)
__global__ __launch_bounds__(256) void agg2_kernel(const float* __restrict__ h2p,
                                                   const int* __restrict__ csr,
                                                   const int* __restrict__ rowptr,
                                                   const int* __restrict__ deg,
                                                   const float* __restrict__ ndst,
                                                   const float* __restrict__ b2,
                                                   float* __restrict__ out) {
    int wid = threadIdx.x >> 6, lane = threadIdx.x & 63;
    int node = blockIdx.x * 4 + wid;
    if (node >= N_NODES) return;
    int rp = rowptr[node], end = rp + deg[node];
    float a0 = 0.f, a1 = 0.f, a2 = 0.f, a3 = 0.f, a4 = 0.f, a5 = 0.f, a6 = 0.f;
    for (int p = rp + lane; p < end; p += 64) {
        int s = csr[p];
        const float4* r = (const float4*)(h2p + (long)s * 8);
        float4 lo = r[0], hi = r[1];
        a0 += lo.x; a1 += lo.y; a2 += lo.z; a3 += lo.w;
        a4 += hi.x; a5 += hi.y; a6 += hi.z;
    }
    float nd = ndst[node];
    float acc[NCLS] = {a0, a1, a2, a3, a4, a5, a6};
#pragma unroll
    for (int c = 0; c < NCLS; c++) {
        float v = acc[c];
#pragma unroll
        for (int off = 1; off < 64; off <<= 1) v += __shfl_xor(v, off);
        if (lane == c) out[(long)node * NCLS + c] = v * nd + b2[c];
    }
}

extern "C" void kernel_launch(void* const* d_in, const int* in_sizes, int n_in,
                              void* d_out, int out_size, void* d_ws, size_t ws_size,
                              hipStream_t stream) {
    const float* X  = (const float*)d_in[0];
    const int* src  = (const int*)d_in[1];
    const int* dst  = (const int*)d_in[2];
    const float* W1 = (const float*)d_in[3];
    const float* b1 = (const float*)d_in[4];
    const float* W2 = (const float*)d_in[5];
    const float* b2 = (const float*)d_in[6];
    float* out = (float*)d_out;

    char* ws = (char*)d_ws;
    int* deg_src = (int*)(ws + O_DEG_SRC);
    int* deg_dst = (int*)(ws + O_DEG_DST);
    int* cursor  = (int*)(ws + O_CURSOR);
    int* rowptr  = (int*)(ws + O_ROWPTR);
    float* nsrc  = (float*)(ws + O_NSRC);
    float* ndst  = (float*)(ws + O_NDST);
    int* bsum    = (int*)(ws + O_BSUM);
    int* boff    = (int*)(ws + O_BOFF);
    int* csr     = (int*)(ws + O_CSR);
    _Float16* h  = (_Float16*)(ws + O_H);
    float* h2p   = (float*)(ws + O_H2);
    _Float16* W1S = (_Float16*)(ws + O_W1S);

    const int nb = (N_NODES + 255) / 256;  // 196
    zero_ws_kernel<<<147, 256, 0, stream>>>((int4*)ws);
    w1prep_kernel<<<(KSTEPS * 4 * 128 + 255) / 256, 256, 0, stream>>>(W1, W1S);
    deg_kernel<<<N_EDGES / 256, 256, 0, stream>>>(dst, deg_dst);
    scan1_kernel<<<nb, 256, 0, stream>>>(deg_dst, rowptr, bsum);
    scan2_kernel<<<1, 256, 0, stream>>>(bsum, boff, nb);
    scan3_kernel<<<nb, 256, 0, stream>>>(rowptr, deg_dst, boff, ndst);
    fill_kernel<<<N_EDGES / 256, 256, 0, stream>>>(src, dst, rowptr, cursor, csr, deg_src);
    nsrc_kernel<<<nb, 256, 0, stream>>>(deg_src, nsrc);

    gemm1_mfma_kernel<<<(N_NODES + GBM - 1) / GBM, 256, 0, stream>>>(X, W1S, nsrc, h);

    agg1_kernel<<<(N_NODES + 15) / 16, 256, 0, stream>>>(h, csr, rowptr, deg_dst, ndst, nsrc,
                                                         b1, W2, h2p);
    agg2_kernel<<<(N_NODES + 3) / 4, 256, 0, stream>>>(h2p, csr, rowptr, deg_dst, ndst, b2, out);
}